// Round 5
// baseline (255.765 us; speedup 1.0000x reference)
//
#include <hip/hip_runtime.h>
#include <hip/hip_bf16.h>

#define B_  8
#define N_  2048
#define KD_ 256
#define AD_ 128
#define VD_ 256
#define SQL2E 1.2011224087864498f   // sqrt(log2(e)); folded into proj so attn uses exp2

using s16x8 = __attribute__((ext_vector_type(8))) short;
using f16x8 = __attribute__((ext_vector_type(8))) _Float16;
using h2    = __attribute__((ext_vector_type(2))) __fp16;
using f32x4 = __attribute__((ext_vector_type(4))) float;

__device__ __forceinline__ f32x4 mfma16(s16x8 a, s16x8 b, f32x4 c) {
  return __builtin_amdgcn_mfma_f32_16x16x32_f16(
      __builtin_bit_cast(f16x8, a), __builtin_bit_cast(f16x8, b), c, 0, 0, 0);
}
__device__ __forceinline__ short f2h(float f) {
  _Float16 h = (_Float16)f;
  return *reinterpret_cast<short*>(&h);
}
__device__ __forceinline__ s16x8 cvt8(const float* __restrict__ p) {
  union { s16x8 v; h2 h[4]; } u;
  f32x4 a = *(const f32x4*)p;
  f32x4 bq = *(const f32x4*)(p + 4);
  u.h[0] = __builtin_amdgcn_cvt_pkrtz(a[0], a[1]);
  u.h[1] = __builtin_amdgcn_cvt_pkrtz(a[2], a[3]);
  u.h[2] = __builtin_amdgcn_cvt_pkrtz(bq[0], bq[1]);
  u.h[3] = __builtin_amdgcn_cvt_pkrtz(bq[2], bq[3]);
  return u.v;
}

// One kernel: prep (transV tile + proj tile per block, XCD-aligned to consumer)
// -> device-scope ticket barrier (512 blocks == guaranteed co-resident at
//    __launch_bounds__(256,2): 2 blocks/CU x 256 CU) -> flash attention.
// Dynamic LDS 51744 B: prep sWT [128][136] overlaps attn sK/sP/sAl.
__global__ __launch_bounds__(256, 2) void fused_k(
    const float* __restrict__ k1, const float* __restrict__ k2,
    const float* __restrict__ v1, const float* __restrict__ v2,
    const float* __restrict__ W1, const float* __restrict__ b1f,
    const float* __restrict__ W2, const float* __restrict__ b2f,
    short* __restrict__ q1p, short* __restrict__ q2p,
    short* __restrict__ vt1, short* __restrict__ vt2,
    float* __restrict__ out, unsigned* cnt) {
  extern __shared__ f32x4 smemv[];
  char* smem = (char*)smemv;

  const int t   = threadIdx.x;
  const int id  = blockIdx.x;
  const int xcd = id & 7, seq = id >> 3;
  const int bp  = xcd * 2 + (seq >> 5);   // (pass,b) this block serves in attn
  const int pb  = bp & 7;                 // b
  const int ph  = bp >> 3;                // pass
  const int j32 = seq & 31;

  // ================= PREP: transV tile (consumer-XCD-local) =================
  {
    const int a = ph ^ 1;                 // vt array consumed by pass=ph
    const float* src = a ? v2 : v1;
    short* dst = a ? vt2 : vt1;
    const size_t base = ((size_t)(pb * 32 + j32)) * (256 * 64);
    const int w = t >> 6, vch = (t >> 4) & 3, l16 = t & 15;
    #pragma unroll
    for (int i = 0; i < 8; i++) {
      float x[8];
      #pragma unroll
      for (int kk = 0; kk < 8; kk++)
        x[kk] = src[((size_t)(pb * N_ + j32 * 64 + i * 8 + kk)) * VD_ + t];
      union { s16x8 v; h2 h[4]; } u;
      #pragma unroll
      for (int kk = 0; kk < 4; kk++)
        u.h[kk] = __builtin_amdgcn_cvt_pkrtz(x[2 * kk], x[2 * kk + 1]);
      int f = vch * 2 + (i >> 2);
      *(s16x8*)&dst[base + (size_t)((w * 8 + f) * 64 + (i & 3) * 16 + l16) * 8] = u.v;
    }
  }
  // ================= PREP: proj tile (K-consumer-XCD-local) =================
  {
    const int z = ph ^ 1;                 // q array read as K by pass=ph
    const float* X    = z ? k2 : k1;
    const float* W    = z ? W2 : W1;
    const float* bias = z ? b2f : b1f;
    short*       Y    = z ? q2p : q1p;
    const int m0 = (pb * 32 + j32) * 64;
    const int lane = t & 63, wave = t >> 6, quad = lane >> 4, l16 = lane & 15;
    short* sWT = (short*)smem;            // [128 n][136] f16, one K-half at a time

    const float* xrow = &X[(size_t)(m0 + wave * 16 + l16) * KD_];
    s16x8 a8[8];
    #pragma unroll
    for (int ks = 0; ks < 8; ks++) a8[ks] = cvt8(xrow + ks * 32 + quad * 8);
    f32x4 acc8[8];
    #pragma unroll
    for (int nt = 0; nt < 8; nt++) acc8[nt] = (f32x4){0.f, 0.f, 0.f, 0.f};
    #pragma unroll
    for (int h = 0; h < 2; h++) {
      #pragma unroll
      for (int j = 0; j < 32; j++) {      // stage W^T half, scaled by SQL2E
        int idx = j * 256 + t, n = idx & 127, kh = idx >> 7;
        const float* wp = &W[(size_t)(h * 128 + kh * 2) * AD_ + n];
        h2 p = __builtin_amdgcn_cvt_pkrtz(wp[0] * SQL2E, wp[AD_] * SQL2E);
        *(h2*)&sWT[n * 136 + kh * 2] = p;
      }
      __syncthreads();
      #pragma unroll
      for (int ks = 0; ks < 4; ks++) {
        #pragma unroll
        for (int nt = 0; nt < 8; nt++) {
          s16x8 bf = *(const s16x8*)&sWT[(nt * 16 + l16) * 136 + ks * 32 + quad * 8];
          acc8[nt] = mfma16(a8[h * 4 + ks], bf, acc8[nt]);
        }
      }
      __syncthreads();
    }
    #pragma unroll
    for (int nt = 0; nt < 8; nt++) {
      float bv = bias[nt * 16 + l16] * SQL2E;
      #pragma unroll
      for (int r = 0; r < 4; r++) {
        int row = m0 + wave * 16 + quad * 4 + r;
        Y[(size_t)row * AD_ + nt * 16 + l16] = f2h(acc8[nt][r] + bv);
      }
    }
  }

  // ============ grid-wide ticket barrier (device-scope, co-resident) ========
  __syncthreads();
  if (t == 0) {
    __threadfence();
    unsigned ticket = atomicAdd(cnt, 1u) + 1u;
    unsigned target = (ticket + 511u) & ~511u;
    while (__hip_atomic_load(cnt, __ATOMIC_RELAXED, __HIP_MEMORY_SCOPE_AGENT) < target)
      __builtin_amdgcn_s_sleep(8);
    __threadfence();
  }
  __syncthreads();

  // ================= ATTENTION (R4 structure + micro) =======================
  {
    const int lane = t & 63, wave = t >> 6, quad = lane >> 4, l16 = lane & 15;
    const int b = pb, pass = ph, q0 = j32 * 64;
    const short* Q  = pass ? q2p : q1p;
    const short* K  = pass ? q1p : q2p;
    const short* Vt = pass ? vt1 : vt2;
    float* O = out + (size_t)pass * ((size_t)B_ * N_ * VD_);

    short* sKb  = (short*)smem;                    // [2][64*136]   34816 B
    short* sPb  = (short*)(smem + 34816);          // [2][4][1024]  16384 B
    float* sAlb = (float*)(smem + 34816 + 16384);  // [2][68]         544 B

    const short* kp = K + (size_t)(b * N_) * AD_ + (size_t)(t >> 4) * AD_ + (t & 15) * 8;
    const short* vp = Vt + (size_t)b * 32 * (256 * 64) + wave * 4096 + lane * 8;

    s16x8 qf[4];
    #pragma unroll
    for (int ks = 0; ks < 4; ks++)
      qf[ks] = *(const s16x8*)&Q[((size_t)(b * N_ + q0 + wave * 16 + l16)) * AD_ +
                                 ks * 32 + quad * 8];

    float m_i = -1e30f, l_i = 0.f;   // log2-domain; l_i quad-partial until epilogue
    f32x4 acc[16];
    #pragma unroll
    for (int c0 = 0; c0 < 16; c0++) acc[c0] = (f32x4){0.f, 0.f, 0.f, 0.f};

    s16x8 pk[4], pv[8];
    auto loadK = [&]() {
      #pragma unroll
      for (int i = 0; i < 4; i++) pk[i] = *(const s16x8*)(kp + i * 16 * AD_);
      kp += 64 * AD_;
    };
    auto loadV = [&]() {
      #pragma unroll
      for (int f = 0; f < 8; f++) pv[f] = *(const s16x8*)(vp + f * 512);
      vp += 256 * 64;
    };
    auto storeK = [&](int cb) {
      short* d = sKb + cb * (64 * 136);
      #pragma unroll
      for (int i = 0; i < 4; i++) {
        int chunk = i * 256 + t, row = chunk >> 4, c8 = chunk & 15;
        *(s16x8*)&d[row * 136 + c8 * 8] = pk[i];
      }
    };

    loadK(); storeK(0); loadK(); loadV();
    __syncthreads();

    int c = 0;
    for (int kt = 0; kt < 32; kt++) {
      const short* sk = sKb + c * (64 * 136);
      f32x4 st[4];
      #pragma unroll
      for (int nt = 0; nt < 4; nt++) st[nt] = (f32x4){0.f, 0.f, 0.f, 0.f};
      __builtin_amdgcn_s_setprio(1);
      #pragma unroll
      for (int ks = 0; ks < 4; ks++) {
        #pragma unroll
        for (int nt = 0; nt < 4; nt++) {
          s16x8 kf = *(const s16x8*)&sk[(nt * 16 + l16) * 136 + ks * 32 + quad * 8];
          st[nt] = mfma16(kf, qf[ks], st[nt]);
        }
      }
      __builtin_amdgcn_s_setprio(0);

      // depth-4 max tree over 16 in-lane scores + quad combine
      float c0 = fmaxf(fmaxf(st[0][0], st[1][0]), fmaxf(st[2][0], st[3][0]));
      float c1 = fmaxf(fmaxf(st[0][1], st[1][1]), fmaxf(st[2][1], st[3][1]));
      float c2 = fmaxf(fmaxf(st[0][2], st[1][2]), fmaxf(st[2][2], st[3][2]));
      float c3 = fmaxf(fmaxf(st[0][3], st[1][3]), fmaxf(st[2][3], st[3][3]));
      float mt = fmaxf(fmaxf(c0, c1), fmaxf(c2, c3));
      mt = fmaxf(mt, __shfl_xor(mt, 16));
      mt = fmaxf(mt, __shfl_xor(mt, 32));

      // defer-max (log2 units): P <= 2^8 before drift, f16-safe
      float alpha = 1.f;
      bool  resc  = !__all(mt - m_i <= 8.f);
      if (resc) {
        float mn = fmaxf(m_i, mt);
        alpha = exp2f(m_i - mn);
        l_i *= alpha;
        m_i  = mn;
      }

      f32x4 psv = (f32x4){0.f, 0.f, 0.f, 0.f};
      #pragma unroll
      for (int nt = 0; nt < 4; nt++) {
        #pragma unroll
        for (int r = 0; r < 4; r++) {
          float p = exp2f(st[nt][r] - m_i);
          st[nt][r] = p;
          psv[r] += p;
        }
      }
      l_i += (psv[0] + psv[1]) + (psv[2] + psv[3]);   // quad-partial; no shfl

      float* sAl = sAlb + c * 68;
      short* sPw = sPb + (c * 4 + wave) * 1024;
      #pragma unroll
      for (int nt = 0; nt < 4; nt++) {
        union { h2 h[2]; uint2 u; } wu;
        wu.h[0] = __builtin_amdgcn_cvt_pkrtz(st[nt][0], st[nt][1]);
        wu.h[1] = __builtin_amdgcn_cvt_pkrtz(st[nt][2], st[nt][3]);
        int cp = (nt * 4 + quad) ^ ((l16 & 7) << 1);
        *(uint2*)&sPw[l16 * 64 + cp * 4] = wu.u;
      }
      if (quad == 0) sAl[wave * 16 + l16] = alpha;
      if (lane == 0) sAl[64 + wave] = resc ? 1.f : 0.f;

      if (kt + 1 < 32) storeK(1 - c);
      __syncthreads();
      if (kt + 2 < 32) loadK();

      f32x4 fl = *(const f32x4*)&sAl[64];
      if (fl[0] + fl[1] + fl[2] + fl[3] != 0.f) {
        #pragma unroll
        for (int m = 0; m < 4; m++) {
          f32x4 aR = *(const f32x4*)&sAl[m * 16 + quad * 4];
          #pragma unroll
          for (int v = 0; v < 4; v++) {
            #pragma unroll
            for (int r = 0; r < 4; r++) acc[m * 4 + v][r] *= aR[r];
          }
        }
      }

      __builtin_amdgcn_s_setprio(1);
      #pragma unroll
      for (int m = 0; m < 4; m++) {
        const short* sPm = sPb + (c * 4 + m) * 1024;
        #pragma unroll
        for (int ks2 = 0; ks2 < 2; ks2++) {
          int cp = (ks2 * 8 + quad * 2) ^ ((l16 & 7) << 1);
          s16x8 af = *(const s16x8*)&sPm[l16 * 64 + cp * 4];
          #pragma unroll
          for (int v = 0; v < 4; v++)
            acc[m * 4 + v] = mfma16(af, pv[v * 2 + ks2], acc[m * 4 + v]);
        }
      }
      __builtin_amdgcn_s_setprio(0);

      if (kt + 1 < 32) loadV();
      c ^= 1;
    }

    // epilogue: combine quad-partial l across quads, share per q-row
    float lf = l_i + __shfl_xor(l_i, 16);
    lf += __shfl_xor(lf, 32);
    if (quad == 0) sAlb[wave * 16 + l16] = lf;
    __syncthreads();
    #pragma unroll
    for (int m = 0; m < 4; m++) {
      f32x4 lv = *(const f32x4*)&sAlb[m * 16 + quad * 4];
      #pragma unroll
      for (int r = 0; r < 4; r++) {
        float inv = 1.f / lv[r];
        int row = q0 + m * 16 + quad * 4 + r;
        #pragma unroll
        for (int v = 0; v < 4; v++)
          O[((size_t)(b * N_ + row)) * VD_ + wave * 64 + v * 16 + l16] =
              acc[m * 4 + v][r] * inv;
      }
    }
  }
}

extern "C" void kernel_launch(void* const* d_in, const int* in_sizes, int n_in,
                              void* d_out, int out_size, void* d_ws, size_t ws_size,
                              hipStream_t stream) {
  const float* k1 = (const float*)d_in[0];
  const float* k2 = (const float*)d_in[1];
  const float* v1 = (const float*)d_in[2];
  const float* v2 = (const float*)d_in[3];
  const float* W1 = (const float*)d_in[4];
  const float* b1 = (const float*)d_in[5];
  const float* W2 = (const float*)d_in[6];
  const float* b2 = (const float*)d_in[7];

  unsigned* cnt = (unsigned*)d_ws;
  short* base = (short*)d_ws + 8;                    // 16 B offset for counter
  short* q1p = base;                                 // 16384*128 f16 (4 MB)
  short* q2p = q1p + (size_t)16384 * 128;
  short* vt1 = q2p + (size_t)16384 * 128;            // 8*32*256*64 f16 (8.4 MB)
  short* vt2 = vt1 + (size_t)B_ * 32 * 256 * 64;
  float* out = (float*)d_out;

  hipMemsetAsync(cnt, 0, 4, stream);
  fused_k<<<dim3(512), dim3(256), 51744, stream>>>(
      k1, k2, v1, v2, W1, b1, W2, b2, q1p, q2p, vt1, vt2, out, cnt);
}

// Round 6
// 185.448 us; speedup vs baseline: 1.3792x; 1.3792x over previous
//
#include <hip/hip_runtime.h>
#include <hip/hip_bf16.h>

#define B_  8
#define N_  2048
#define KD_ 256
#define AD_ 128
#define VD_ 256
#define SQL2E 1.2011224087864498f   // sqrt(log2(e)); folded into proj so attn uses exp2

using s16x8 = __attribute__((ext_vector_type(8))) short;
using f16x8 = __attribute__((ext_vector_type(8))) _Float16;
using h2    = __attribute__((ext_vector_type(2))) __fp16;
using f32x4 = __attribute__((ext_vector_type(4))) float;

__device__ __forceinline__ f32x4 mfma16(s16x8 a, s16x8 b, f32x4 c) {
  return __builtin_amdgcn_mfma_f32_16x16x32_f16(
      __builtin_bit_cast(f16x8, a), __builtin_bit_cast(f16x8, b), c, 0, 0, 0);
}
__device__ __forceinline__ short f2h(float f) {
  _Float16 h = (_Float16)f;
  return *reinterpret_cast<short*>(&h);
}
__device__ __forceinline__ s16x8 cvt8(const float* __restrict__ p) {
  union { s16x8 v; h2 h[4]; } u;
  f32x4 a = *(const f32x4*)p;
  f32x4 bq = *(const f32x4*)(p + 4);
  u.h[0] = __builtin_amdgcn_cvt_pkrtz(a[0], a[1]);
  u.h[1] = __builtin_amdgcn_cvt_pkrtz(a[2], a[3]);
  u.h[2] = __builtin_amdgcn_cvt_pkrtz(bq[0], bq[1]);
  u.h[3] = __builtin_amdgcn_cvt_pkrtz(bq[2], bq[3]);
  return u.v;
}

// ---------------- fused prep (R4 structure, W/bias scaled by SQL2E) ---------
// blocks [0,512): transV role  -> vt (B-frag-major f16)
// blocks [512,1024): proj role -> q1p/q2p = f16(SQL2E*(X@W + bias))
__global__ __launch_bounds__(256) void prep_k(
    const float* __restrict__ k1, const float* __restrict__ k2,
    const float* __restrict__ v1, const float* __restrict__ v2,
    const float* __restrict__ W1, const float* __restrict__ b1f,
    const float* __restrict__ W2, const float* __restrict__ b2f,
    short* __restrict__ q1p, short* __restrict__ q2p,
    short* __restrict__ vt1, short* __restrict__ vt2) {
  __shared__ __align__(16) short sWT[128 * 264];   // proj role only
  const int t  = threadIdx.x;
  const int id = blockIdx.x;

  if (id < 512) {
    const int kt = id & 31, b = (id >> 5) & 7, z = id >> 8;
    const float* src = z ? v2 : v1;
    short*       dst = z ? vt2 : vt1;
    const size_t base = ((size_t)(b * 32 + kt)) * (256 * 64);
    const int w = t >> 6, vchunk = (t >> 4) & 3, l16 = t & 15;
    #pragma unroll
    for (int i = 0; i < 8; i++) {
      float x[8];
      #pragma unroll
      for (int kk = 0; kk < 8; kk++)
        x[kk] = src[((size_t)(b * N_ + kt * 64 + i * 8 + kk)) * VD_ + t];
      union { s16x8 v; h2 h[4]; } u;
      #pragma unroll
      for (int kk = 0; kk < 4; kk++)
        u.h[kk] = __builtin_amdgcn_cvt_pkrtz(x[2 * kk], x[2 * kk + 1]);
      int f = vchunk * 2 + (i >> 2);
      *(s16x8*)&dst[base + (size_t)((w * 8 + f) * 64 + (i & 3) * 16 + l16) * 8] = u.v;
    }
    return;
  }

  const int pid = id - 512;
  const int z = pid >> 8, mb = pid & 255;
  const float* X    = z ? k2 : k1;
  const float* W    = z ? W2 : W1;
  const float* bias = z ? b2f : b1f;
  short*       Y    = z ? q2p : q1p;
  const int m0   = mb * 64;
  const int lane = t & 63, wave = t >> 6, quad = lane >> 4, l16 = lane & 15;

  #pragma unroll
  for (int j = 0; j < 64; j++) {
    int idx = j * 256 + t;
    int n = idx & 127, kh = idx >> 7;
    h2 p = __builtin_amdgcn_cvt_pkrtz(W[(size_t)(2 * kh) * AD_ + n] * SQL2E,
                                      W[(size_t)(2 * kh + 1) * AD_ + n] * SQL2E);
    *(h2*)&sWT[n * 264 + kh * 2] = p;
  }
  const float* xrow = &X[(size_t)(m0 + wave * 16 + l16) * KD_];
  s16x8 a[8];
  #pragma unroll
  for (int ks = 0; ks < 8; ks++) a[ks] = cvt8(xrow + ks * 32 + quad * 8);
  __syncthreads();

  f32x4 acc[8];
  #pragma unroll
  for (int nt = 0; nt < 8; nt++) acc[nt] = (f32x4){0.f, 0.f, 0.f, 0.f};
  #pragma unroll
  for (int ks = 0; ks < 8; ks++) {
    #pragma unroll
    for (int nt = 0; nt < 8; nt++) {
      s16x8 bf = *(const s16x8*)&sWT[(nt * 16 + l16) * 264 + ks * 32 + quad * 8];
      acc[nt] = mfma16(a[ks], bf, acc[nt]);
    }
  }
  #pragma unroll
  for (int nt = 0; nt < 8; nt++) {
    float bv = bias[nt * 16 + l16] * SQL2E;
    #pragma unroll
    for (int r = 0; r < 4; r++) {
      int row = m0 + wave * 16 + quad * 4 + r;
      Y[(size_t)row * AD_ + nt * 16 + l16] = f2h(acc[nt][r] + bv);
    }
  }
}

// ---------------- flash attention, T15 re-phased window ---------------------
// Window i: [barrier] -> QK(i+1) -> rescale -> PV(i) -> softmax(i+1) -> stage.
// PV(i) is independent of softmax(i+1): softmax VALU executes in the MFMA
// shadow (within-wave dual-pipe overlap). Tile t lives in sK/sP/sAl[t&1].
__global__ __launch_bounds__(256, 2) void attn_k(
    const short* __restrict__ q1p, const short* __restrict__ q2p,
    const short* __restrict__ vt1, const short* __restrict__ vt2,
    float* __restrict__ out) {
  __shared__ __align__(16) short sK[2][64 * 136];    // 34816 B
  __shared__ __align__(16) short sP[2][4][16 * 64];  // 16384 B, XOR-swizzled
  __shared__ __align__(16) float sAl[2][68];         // alpha[64] + flags[4]

  const int t    = threadIdx.x;
  const int lane = t & 63, wave = t >> 6, quad = lane >> 4, l16 = lane & 15;
  const int id   = blockIdx.x;
  const int xcd  = id & 7, seq = id >> 3;
  const int bp   = xcd * 2 + (seq >> 5);
  const int qb   = seq & 31;
  const int b    = bp & 7, pass = bp >> 3;
  const int q0   = qb * 64;
  const short* Q  = pass ? q2p : q1p;
  const short* K  = pass ? q1p : q2p;
  const short* Vt = pass ? vt1 : vt2;
  float* O = out + (size_t)pass * ((size_t)B_ * N_ * VD_);

  const short* kp = K + (size_t)(b * N_) * AD_ + (size_t)(t >> 4) * AD_ + (t & 15) * 8;
  const short* vp = Vt + (size_t)b * 32 * (256 * 64) + wave * 4096 + lane * 8;

  s16x8 qf[4];
  #pragma unroll
  for (int ks = 0; ks < 4; ks++)
    qf[ks] = *(const s16x8*)&Q[((size_t)(b * N_ + q0 + wave * 16 + l16)) * AD_ +
                               ks * 32 + quad * 8];

  float m_i = -1e30f, l_i = 0.f;   // log2 domain; l_i quad-partial till epilogue
  f32x4 acc[16];
  #pragma unroll
  for (int c0 = 0; c0 < 16; c0++) acc[c0] = (f32x4){0.f, 0.f, 0.f, 0.f};

  s16x8 pk[4], pv[8];
  auto loadK = [&]() {
    #pragma unroll
    for (int i = 0; i < 4; i++) pk[i] = *(const s16x8*)(kp + i * 16 * AD_);
    kp += 64 * AD_;
  };
  auto loadV = [&]() {
    #pragma unroll
    for (int f = 0; f < 8; f++) pv[f] = *(const s16x8*)(vp + f * 512);
    vp += 256 * 64;
  };
  auto storeK = [&](int cb) {
    #pragma unroll
    for (int i = 0; i < 4; i++) {
      int chunk = i * 256 + t, row = chunk >> 4, c8 = chunk & 15;
      *(s16x8*)&sK[cb][row * 136 + c8 * 8] = pk[i];
    }
  };
  auto qk = [&](int cb, f32x4* st) {
    #pragma unroll
    for (int nt = 0; nt < 4; nt++) st[nt] = (f32x4){0.f, 0.f, 0.f, 0.f};
    __builtin_amdgcn_s_setprio(1);
    #pragma unroll
    for (int ks = 0; ks < 4; ks++) {
      #pragma unroll
      for (int nt = 0; nt < 4; nt++) {
        s16x8 kf = *(const s16x8*)&sK[cb][(nt * 16 + l16) * 136 + ks * 32 + quad * 8];
        st[nt] = mfma16(kf, qf[ks], st[nt]);
      }
    }
    __builtin_amdgcn_s_setprio(0);
  };
  auto softmax_store = [&](f32x4* st, int cb) {
    // flat depth-4 max tree over 16 in-lane scores + quad combine
    float c0 = fmaxf(fmaxf(st[0][0], st[1][0]), fmaxf(st[2][0], st[3][0]));
    float c1 = fmaxf(fmaxf(st[0][1], st[1][1]), fmaxf(st[2][1], st[3][1]));
    float c2 = fmaxf(fmaxf(st[0][2], st[1][2]), fmaxf(st[2][2], st[3][2]));
    float c3 = fmaxf(fmaxf(st[0][3], st[1][3]), fmaxf(st[2][3], st[3][3]));
    float mt = fmaxf(fmaxf(c0, c1), fmaxf(c2, c3));
    mt = fmaxf(mt, __shfl_xor(mt, 16));
    mt = fmaxf(mt, __shfl_xor(mt, 32));
    // defer-max (log2 units): P <= 2^8 before refresh, f16-safe
    float alpha = 1.f;
    bool  resc  = !__all(mt - m_i <= 8.f);
    if (resc) {
      float mn = fmaxf(m_i, mt);
      alpha = exp2f(m_i - mn);
      l_i *= alpha;
      m_i  = mn;
    }
    f32x4 psv = (f32x4){0.f, 0.f, 0.f, 0.f};
    #pragma unroll
    for (int nt = 0; nt < 4; nt++) {
      #pragma unroll
      for (int r = 0; r < 4; r++) {
        float p = exp2f(st[nt][r] - m_i);
        st[nt][r] = p;
        psv[r] += p;
      }
    }
    l_i += (psv[0] + psv[1]) + (psv[2] + psv[3]);   // quad-partial; no shfl
    #pragma unroll
    for (int nt = 0; nt < 4; nt++) {
      union { h2 h[2]; uint2 u; } wu;
      wu.h[0] = __builtin_amdgcn_cvt_pkrtz(st[nt][0], st[nt][1]);
      wu.h[1] = __builtin_amdgcn_cvt_pkrtz(st[nt][2], st[nt][3]);
      int cp = (nt * 4 + quad) ^ ((l16 & 7) << 1);
      *(uint2*)&sP[cb][wave][l16 * 64 + cp * 4] = wu.u;
    }
    if (quad == 0) sAl[cb][wave * 16 + l16] = alpha;
    if (lane == 0) sAl[cb][64 + wave] = resc ? 1.f : 0.f;
  };

  // prologue: tiles 0,1 staged; scores(0) computed into sP[0]/sAl[0]
  loadK(); storeK(0); loadK(); loadV();
  __syncthreads();
  {
    f32x4 st[4];
    qk(0, st);
    softmax_store(st, 0);
  }
  storeK(1);   // pk held K(1)
  loadK();     // pk <- K(2)

  for (int i = 0; i < 32; i++) {
    const int c = i & 1;
    __syncthreads();

    // QK for NEXT tile (sK[1-c] committed last window)
    f32x4 st[4];
    if (i + 1 < 32) qk(1 - c, st);

    // cross-wave acc rescale for tile i (alpha from last window's softmax)
    f32x4 fl = *(const f32x4*)&sAl[c][64];
    if (fl[0] + fl[1] + fl[2] + fl[3] != 0.f) {
      #pragma unroll
      for (int m = 0; m < 4; m++) {
        f32x4 aR = *(const f32x4*)&sAl[c][m * 16 + quad * 4];
        #pragma unroll
        for (int v = 0; v < 4; v++) {
          #pragma unroll
          for (int r = 0; r < 4; r++) acc[m * 4 + v][r] *= aR[r];
        }
      }
    }

    // PV(i): independent of softmax(i+1) below -> dual-pipe overlap
    __builtin_amdgcn_s_setprio(1);
    #pragma unroll
    for (int m = 0; m < 4; m++) {
      #pragma unroll
      for (int ks2 = 0; ks2 < 2; ks2++) {
        int cp = (ks2 * 8 + quad * 2) ^ ((l16 & 7) << 1);
        s16x8 af = *(const s16x8*)&sP[c][m][l16 * 64 + cp * 4];
        #pragma unroll
        for (int v = 0; v < 4; v++)
          acc[m * 4 + v] = mfma16(af, pv[v * 2 + ks2], acc[m * 4 + v]);
      }
    }
    __builtin_amdgcn_s_setprio(0);

    // softmax(i+1) -> sP[1-c]/sAl[1-c] (read next window, after barrier)
    if (i + 1 < 32) softmax_store(st, 1 - c);

    // stage tile i+2 into sK[c]; refill pk with tile i+3
    if (i + 2 < 32) storeK(c);
    if (i + 3 < 32) loadK();
    if (i + 1 < 32) loadV();
  }

  // epilogue: combine quad-partial l across quads, share per q-row
  float lf = l_i + __shfl_xor(l_i, 16);
  lf += __shfl_xor(lf, 32);
  if (quad == 0) sAl[0][wave * 16 + l16] = lf;
  __syncthreads();
  #pragma unroll
  for (int m = 0; m < 4; m++) {
    f32x4 lv = *(const f32x4*)&sAl[0][m * 16 + quad * 4];
    #pragma unroll
    for (int r = 0; r < 4; r++) {
      float inv = 1.f / lv[r];
      int row = q0 + m * 16 + quad * 4 + r;
      #pragma unroll
      for (int v = 0; v < 4; v++)
        O[((size_t)(b * N_ + row)) * VD_ + wave * 64 + v * 16 + l16] =
            acc[m * 4 + v][r] * inv;
    }
  }
}

extern "C" void kernel_launch(void* const* d_in, const int* in_sizes, int n_in,
                              void* d_out, int out_size, void* d_ws, size_t ws_size,
                              hipStream_t stream) {
  const float* k1 = (const float*)d_in[0];
  const float* k2 = (const float*)d_in[1];
  const float* v1 = (const float*)d_in[2];
  const float* v2 = (const float*)d_in[3];
  const float* W1 = (const float*)d_in[4];
  const float* b1 = (const float*)d_in[5];
  const float* W2 = (const float*)d_in[6];
  const float* b2 = (const float*)d_in[7];

  short* ws  = (short*)d_ws;
  short* q1p = ws;                                   // 16384*128 f16 (4 MB)
  short* q2p = q1p + (size_t)16384 * 128;
  short* vt1 = q2p + (size_t)16384 * 128;            // 8*32*256*64 f16 (8.4 MB)
  short* vt2 = vt1 + (size_t)B_ * 32 * 256 * 64;
  float* out = (float*)d_out;

  prep_k<<<dim3(1024), dim3(256), 0, stream>>>(k1, k2, v1, v2, W1, b1, W2, b2,
                                               q1p, q2p, vt1, vt2);
  attn_k<<<dim3(512), dim3(256), 0, stream>>>(q1p, q2p, vt1, vt2, out);
}

// Round 7
// 185.089 us; speedup vs baseline: 1.3819x; 1.0019x over previous
//
#include <hip/hip_runtime.h>
#include <hip/hip_bf16.h>

#define B_  8
#define N_  2048
#define KD_ 256
#define AD_ 128
#define VD_ 256
#define SQL2E 1.2011224087864498f   // sqrt(log2(e)); folded into proj so attn uses exp2

using s16x8 = __attribute__((ext_vector_type(8))) short;
using f16x8 = __attribute__((ext_vector_type(8))) _Float16;
using h2    = __attribute__((ext_vector_type(2))) __fp16;
using f32x4 = __attribute__((ext_vector_type(4))) float;

__device__ __forceinline__ f32x4 mfma16(s16x8 a, s16x8 b, f32x4 c) {
  return __builtin_amdgcn_mfma_f32_16x16x32_f16(
      __builtin_bit_cast(f16x8, a), __builtin_bit_cast(f16x8, b), c, 0, 0, 0);
}
__device__ __forceinline__ short f2h(float f) {
  _Float16 h = (_Float16)f;
  return *reinterpret_cast<short*>(&h);
}
__device__ __forceinline__ s16x8 cvt8(const float* __restrict__ p) {
  union { s16x8 v; h2 h[4]; } u;
  f32x4 a = *(const f32x4*)p;
  f32x4 bq = *(const f32x4*)(p + 4);
  u.h[0] = __builtin_amdgcn_cvt_pkrtz(a[0], a[1]);
  u.h[1] = __builtin_amdgcn_cvt_pkrtz(a[2], a[3]);
  u.h[2] = __builtin_amdgcn_cvt_pkrtz(bq[0], bq[1]);
  u.h[3] = __builtin_amdgcn_cvt_pkrtz(bq[2], bq[3]);
  return u.v;
}

// ---------------- fused prep (W/bias scaled by SQL2E) -----------------------
// blocks [0,512): transV role  -> vt (B-frag-major f16)
// blocks [512,1024): proj role -> q1p/q2p = f16(SQL2E*(X@W + bias))
__global__ __launch_bounds__(256) void prep_k(
    const float* __restrict__ k1, const float* __restrict__ k2,
    const float* __restrict__ v1, const float* __restrict__ v2,
    const float* __restrict__ W1, const float* __restrict__ b1f,
    const float* __restrict__ W2, const float* __restrict__ b2f,
    short* __restrict__ q1p, short* __restrict__ q2p,
    short* __restrict__ vt1, short* __restrict__ vt2) {
  __shared__ __align__(16) short sWT[128 * 264];   // proj role only
  const int t  = threadIdx.x;
  const int id = blockIdx.x;

  if (id < 512) {
    const int kt = id & 31, b = (id >> 5) & 7, z = id >> 8;
    const float* src = z ? v2 : v1;
    short*       dst = z ? vt2 : vt1;
    const size_t base = ((size_t)(b * 32 + kt)) * (256 * 64);
    const int w = t >> 6, vchunk = (t >> 4) & 3, l16 = t & 15;
    #pragma unroll
    for (int i = 0; i < 8; i++) {
      float x[8];
      #pragma unroll
      for (int kk = 0; kk < 8; kk++)
        x[kk] = src[((size_t)(b * N_ + kt * 64 + i * 8 + kk)) * VD_ + t];
      union { s16x8 v; h2 h[4]; } u;
      #pragma unroll
      for (int kk = 0; kk < 4; kk++)
        u.h[kk] = __builtin_amdgcn_cvt_pkrtz(x[2 * kk], x[2 * kk + 1]);
      int f = vchunk * 2 + (i >> 2);
      *(s16x8*)&dst[base + (size_t)((w * 8 + f) * 64 + (i & 3) * 16 + l16) * 8] = u.v;
    }
    return;
  }

  const int pid = id - 512;
  const int z = pid >> 8, mb = pid & 255;
  const float* X    = z ? k2 : k1;
  const float* W    = z ? W2 : W1;
  const float* bias = z ? b2f : b1f;
  short*       Y    = z ? q2p : q1p;
  const int m0   = mb * 64;
  const int lane = t & 63, wave = t >> 6, quad = lane >> 4, l16 = lane & 15;

  #pragma unroll
  for (int j = 0; j < 64; j++) {
    int idx = j * 256 + t;
    int n = idx & 127, kh = idx >> 7;
    h2 p = __builtin_amdgcn_cvt_pkrtz(W[(size_t)(2 * kh) * AD_ + n] * SQL2E,
                                      W[(size_t)(2 * kh + 1) * AD_ + n] * SQL2E);
    *(h2*)&sWT[n * 264 + kh * 2] = p;
  }
  const float* xrow = &X[(size_t)(m0 + wave * 16 + l16) * KD_];
  s16x8 a[8];
  #pragma unroll
  for (int ks = 0; ks < 8; ks++) a[ks] = cvt8(xrow + ks * 32 + quad * 8);
  __syncthreads();

  f32x4 acc[8];
  #pragma unroll
  for (int nt = 0; nt < 8; nt++) acc[nt] = (f32x4){0.f, 0.f, 0.f, 0.f};
  #pragma unroll
  for (int ks = 0; ks < 8; ks++) {
    #pragma unroll
    for (int nt = 0; nt < 8; nt++) {
      s16x8 bf = *(const s16x8*)&sWT[(nt * 16 + l16) * 264 + ks * 32 + quad * 8];
      acc[nt] = mfma16(a[ks], bf, acc[nt]);
    }
  }
  #pragma unroll
  for (int nt = 0; nt < 8; nt++) {
    float bv = bias[nt * 16 + l16] * SQL2E;
    #pragma unroll
    for (int r = 0; r < 4; r++) {
      int row = m0 + wave * 16 + quad * 4 + r;
      Y[(size_t)row * AD_ + nt * 16 + l16] = f2h(acc[nt][r] + bv);
    }
  }
}

// ---------------- flash attention: R4 schedule + R6 micro -------------------
// Window: QK(i) -> softmax(i) -> storeK -> [barrier] -> loadK(i+2) ->
//         rescale -> PV(i) -> loadV(i+1).  (best-measured schedule, R4)
// Micro: exp2 (scale folded in proj), flat fmax tree, epilogue-deferred l-sum.
__global__ __launch_bounds__(256, 2) void attn_k(
    const short* __restrict__ q1p, const short* __restrict__ q2p,
    const short* __restrict__ vt1, const short* __restrict__ vt2,
    float* __restrict__ out) {
  __shared__ __align__(16) short sK[2][64 * 136];    // 34816 B
  __shared__ __align__(16) short sP[2][4][16 * 64];  // 16384 B, XOR-swizzled
  __shared__ __align__(16) float sAl[2][68];         // alpha[64] + flags[4]

  const int t    = threadIdx.x;
  const int lane = t & 63, wave = t >> 6, quad = lane >> 4, l16 = lane & 15;
  const int id   = blockIdx.x;
  const int xcd  = id & 7, seq = id >> 3;
  const int bp   = xcd * 2 + (seq >> 5);
  const int qb   = seq & 31;
  const int b    = bp & 7, pass = bp >> 3;
  const int q0   = qb * 64;
  const short* Q  = pass ? q2p : q1p;
  const short* K  = pass ? q1p : q2p;
  const short* Vt = pass ? vt1 : vt2;
  float* O = out + (size_t)pass * ((size_t)B_ * N_ * VD_);

  const short* kp = K + (size_t)(b * N_) * AD_ + (size_t)(t >> 4) * AD_ + (t & 15) * 8;
  const short* vp = Vt + (size_t)b * 32 * (256 * 64) + wave * 4096 + lane * 8;

  s16x8 qf[4];
  #pragma unroll
  for (int ks = 0; ks < 4; ks++)
    qf[ks] = *(const s16x8*)&Q[((size_t)(b * N_ + q0 + wave * 16 + l16)) * AD_ +
                               ks * 32 + quad * 8];

  float m_i = -1e30f, l_i = 0.f;   // log2 domain; l_i quad-partial till epilogue
  f32x4 acc[16];
  #pragma unroll
  for (int c0 = 0; c0 < 16; c0++) acc[c0] = (f32x4){0.f, 0.f, 0.f, 0.f};

  s16x8 pk[4], pv[8];
  auto loadK = [&]() {
    #pragma unroll
    for (int i = 0; i < 4; i++) pk[i] = *(const s16x8*)(kp + i * 16 * AD_);
    kp += 64 * AD_;
  };
  auto loadV = [&]() {
    #pragma unroll
    for (int f = 0; f < 8; f++) pv[f] = *(const s16x8*)(vp + f * 512);
    vp += 256 * 64;
  };
  auto storeK = [&](int cb) {
    #pragma unroll
    for (int i = 0; i < 4; i++) {
      int chunk = i * 256 + t, row = chunk >> 4, c8 = chunk & 15;
      *(s16x8*)&sK[cb][row * 136 + c8 * 8] = pk[i];
    }
  };

  // prologue: sK[0] <- K(0); pk <- K(1); pv <- V(0)
  loadK(); storeK(0); loadK(); loadV();
  __syncthreads();

  int c = 0;
  for (int kt = 0; kt < 32; kt++) {
    // S^T = K Q^T : st[nt] = S[key = nt*16+quad*4+r][q = wave*16 + l16]
    f32x4 st[4];
    #pragma unroll
    for (int nt = 0; nt < 4; nt++) st[nt] = (f32x4){0.f, 0.f, 0.f, 0.f};
    __builtin_amdgcn_s_setprio(1);
    #pragma unroll
    for (int ks = 0; ks < 4; ks++) {
      #pragma unroll
      for (int nt = 0; nt < 4; nt++) {
        s16x8 kf = *(const s16x8*)&sK[c][(nt * 16 + l16) * 136 + ks * 32 + quad * 8];
        st[nt] = mfma16(kf, qf[ks], st[nt]);
      }
    }
    __builtin_amdgcn_s_setprio(0);

    // flat depth-4 max tree over 16 in-lane scores + quad combine
    float c0 = fmaxf(fmaxf(st[0][0], st[1][0]), fmaxf(st[2][0], st[3][0]));
    float c1 = fmaxf(fmaxf(st[0][1], st[1][1]), fmaxf(st[2][1], st[3][1]));
    float c2 = fmaxf(fmaxf(st[0][2], st[1][2]), fmaxf(st[2][2], st[3][2]));
    float c3 = fmaxf(fmaxf(st[0][3], st[1][3]), fmaxf(st[2][3], st[3][3]));
    float mt = fmaxf(fmaxf(c0, c1), fmaxf(c2, c3));
    mt = fmaxf(mt, __shfl_xor(mt, 16));
    mt = fmaxf(mt, __shfl_xor(mt, 32));

    // defer-max (log2 units): P <= 2^8 before refresh, f16-safe
    float alpha = 1.f;
    bool  resc  = !__all(mt - m_i <= 8.f);
    if (resc) {
      float mn = fmaxf(m_i, mt);
      alpha = exp2f(m_i - mn);
      l_i *= alpha;
      m_i  = mn;
    }

    // p = exp2(s - m_i); quad-partial row sums deferred to epilogue
    f32x4 psv = (f32x4){0.f, 0.f, 0.f, 0.f};
    #pragma unroll
    for (int nt = 0; nt < 4; nt++) {
      #pragma unroll
      for (int r = 0; r < 4; r++) {
        float p = exp2f(st[nt][r] - m_i);
        st[nt][r] = p;
        psv[r] += p;
      }
    }
    l_i += (psv[0] + psv[1]) + (psv[2] + psv[3]);

    // pack P pairs -> 8B swizzled writes into shared sP[c][wave]
    #pragma unroll
    for (int nt = 0; nt < 4; nt++) {
      union { h2 h[2]; uint2 u; } wu;
      wu.h[0] = __builtin_amdgcn_cvt_pkrtz(st[nt][0], st[nt][1]);
      wu.h[1] = __builtin_amdgcn_cvt_pkrtz(st[nt][2], st[nt][3]);
      int cp = (nt * 4 + quad) ^ ((l16 & 7) << 1);
      *(uint2*)&sP[c][wave][l16 * 64 + cp * 4] = wu.u;
    }
    if (quad == 0) sAl[c][wave * 16 + l16] = alpha;
    if (lane == 0) sAl[c][64 + wave] = resc ? 1.f : 0.f;

    // commit next K tile into the other buffer (pk already in regs)
    if (kt + 1 < 32) storeK(1 - c);

    __syncthreads();

    // prefetch K(kt+2) AFTER the barrier so the drain never waits on it
    if (kt + 2 < 32) loadK();

    // cross-wave acc rescale (rare: flag word is a broadcast read)
    f32x4 fl = *(const f32x4*)&sAl[c][64];
    if (fl[0] + fl[1] + fl[2] + fl[3] != 0.f) {
      #pragma unroll
      for (int m = 0; m < 4; m++) {
        f32x4 aR = *(const f32x4*)&sAl[c][m * 16 + quad * 4];
        #pragma unroll
        for (int v = 0; v < 4; v++) {
          #pragma unroll
          for (int r = 0; r < 4; r++) acc[m * 4 + v][r] *= aR[r];
        }
      }
    }

    // O[q][v-slice of this wave] += P @ V   (af: LDS broadcast; bf: registers)
    __builtin_amdgcn_s_setprio(1);
    #pragma unroll
    for (int m = 0; m < 4; m++) {
      #pragma unroll
      for (int ks2 = 0; ks2 < 2; ks2++) {
        int cp = (ks2 * 8 + quad * 2) ^ ((l16 & 7) << 1);
        s16x8 af = *(const s16x8*)&sP[c][m][l16 * 64 + cp * 4];
        #pragma unroll
        for (int v = 0; v < 4; v++)
          acc[m * 4 + v] = mfma16(af, pv[v * 2 + ks2], acc[m * 4 + v]);
      }
    }
    __builtin_amdgcn_s_setprio(0);

    // stream next V tile into registers (consumed after next barrier)
    if (kt + 1 < 32) loadV();
    c ^= 1;
  }

  // epilogue: combine quad-partial l across quads, share per q-row
  float lf = l_i + __shfl_xor(l_i, 16);
  lf += __shfl_xor(lf, 32);
  if (quad == 0) sAl[0][wave * 16 + l16] = lf;
  __syncthreads();
  #pragma unroll
  for (int m = 0; m < 4; m++) {
    f32x4 lv = *(const f32x4*)&sAl[0][m * 16 + quad * 4];
    #pragma unroll
    for (int r = 0; r < 4; r++) {
      float inv = 1.f / lv[r];
      int row = q0 + m * 16 + quad * 4 + r;
      #pragma unroll
      for (int v = 0; v < 4; v++)
        O[((size_t)(b * N_ + row)) * VD_ + wave * 64 + v * 16 + l16] =
            acc[m * 4 + v][r] * inv;
    }
  }
}

extern "C" void kernel_launch(void* const* d_in, const int* in_sizes, int n_in,
                              void* d_out, int out_size, void* d_ws, size_t ws_size,
                              hipStream_t stream) {
  const float* k1 = (const float*)d_in[0];
  const float* k2 = (const float*)d_in[1];
  const float* v1 = (const float*)d_in[2];
  const float* v2 = (const float*)d_in[3];
  const float* W1 = (const float*)d_in[4];
  const float* b1 = (const float*)d_in[5];
  const float* W2 = (const float*)d_in[6];
  const float* b2 = (const float*)d_in[7];

  short* ws  = (short*)d_ws;
  short* q1p = ws;                                   // 16384*128 f16 (4 MB)
  short* q2p = q1p + (size_t)16384 * 128;
  short* vt1 = q2p + (size_t)16384 * 128;            // 8*32*256*64 f16 (8.4 MB)
  short* vt2 = vt1 + (size_t)B_ * 32 * 256 * 64;
  float* out = (float*)d_out;

  prep_k<<<dim3(1024), dim3(256), 0, stream>>>(k1, k2, v1, v2, W1, b1, W2, b2,
                                               q1p, q2p, vt1, vt2);
  attn_k<<<dim3(512), dim3(256), 0, stream>>>(q1p, q2p, vt1, vt2, out);
}

// Round 8
// 180.854 us; speedup vs baseline: 1.4142x; 1.0234x over previous
//
#include <hip/hip_runtime.h>
#include <hip/hip_bf16.h>

#define B_  8
#define N_  2048
#define KD_ 256
#define AD_ 128
#define VD_ 256
#define SQL2E 1.2011224087864498f   // sqrt(log2(e)); folded into proj so attn uses exp2

using s16x8 = __attribute__((ext_vector_type(8))) short;
using f16x8 = __attribute__((ext_vector_type(8))) _Float16;
using h2    = __attribute__((ext_vector_type(2))) __fp16;
using f32x4 = __attribute__((ext_vector_type(4))) float;

__device__ __forceinline__ f32x4 mfma16(s16x8 a, s16x8 b, f32x4 c) {
  return __builtin_amdgcn_mfma_f32_16x16x32_f16(
      __builtin_bit_cast(f16x8, a), __builtin_bit_cast(f16x8, b), c, 0, 0, 0);
}
__device__ __forceinline__ short f2h(float f) {
  _Float16 h = (_Float16)f;
  return *reinterpret_cast<short*>(&h);
}
// raw hardware exp2 (v_exp_f32): 1 VALU op. libm exp2f w/o fast-math takes the
// OCML precise path (subnormal fixup, ~6-8 ops) -- that was R6/R7's regression.
__device__ __forceinline__ float exp2_hw(float x) {
#if __has_builtin(__builtin_amdgcn_exp2f)
  return __builtin_amdgcn_exp2f(x);
#else
  float r;
  asm volatile("v_exp_f32 %0, %1" : "=v"(r) : "v"(x));
  return r;
#endif
}
__device__ __forceinline__ s16x8 cvt8(const float* __restrict__ p) {
  union { s16x8 v; h2 h[4]; } u;
  f32x4 a = *(const f32x4*)p;
  f32x4 bq = *(const f32x4*)(p + 4);
  u.h[0] = __builtin_amdgcn_cvt_pkrtz(a[0], a[1]);
  u.h[1] = __builtin_amdgcn_cvt_pkrtz(a[2], a[3]);
  u.h[2] = __builtin_amdgcn_cvt_pkrtz(bq[0], bq[1]);
  u.h[3] = __builtin_amdgcn_cvt_pkrtz(bq[2], bq[3]);
  return u.v;
}

// ---------------- fused prep (W/bias scaled by SQL2E) -----------------------
// blocks [0,512): transV role  -> vt (B-frag-major f16)
// blocks [512,1024): proj role -> q1p/q2p = f16(SQL2E*(X@W + bias))
__global__ __launch_bounds__(256) void prep_k(
    const float* __restrict__ k1, const float* __restrict__ k2,
    const float* __restrict__ v1, const float* __restrict__ v2,
    const float* __restrict__ W1, const float* __restrict__ b1f,
    const float* __restrict__ W2, const float* __restrict__ b2f,
    short* __restrict__ q1p, short* __restrict__ q2p,
    short* __restrict__ vt1, short* __restrict__ vt2) {
  __shared__ __align__(16) short sWT[128 * 264];   // proj role only
  const int t  = threadIdx.x;
  const int id = blockIdx.x;

  if (id < 512) {
    const int kt = id & 31, b = (id >> 5) & 7, z = id >> 8;
    const float* src = z ? v2 : v1;
    short*       dst = z ? vt2 : vt1;
    const size_t base = ((size_t)(b * 32 + kt)) * (256 * 64);
    const int w = t >> 6, vchunk = (t >> 4) & 3, l16 = t & 15;
    #pragma unroll
    for (int i = 0; i < 8; i++) {
      float x[8];
      #pragma unroll
      for (int kk = 0; kk < 8; kk++)
        x[kk] = src[((size_t)(b * N_ + kt * 64 + i * 8 + kk)) * VD_ + t];
      union { s16x8 v; h2 h[4]; } u;
      #pragma unroll
      for (int kk = 0; kk < 4; kk++)
        u.h[kk] = __builtin_amdgcn_cvt_pkrtz(x[2 * kk], x[2 * kk + 1]);
      int f = vchunk * 2 + (i >> 2);
      *(s16x8*)&dst[base + (size_t)((w * 8 + f) * 64 + (i & 3) * 16 + l16) * 8] = u.v;
    }
    return;
  }

  const int pid = id - 512;
  const int z = pid >> 8, mb = pid & 255;
  const float* X    = z ? k2 : k1;
  const float* W    = z ? W2 : W1;
  const float* bias = z ? b2f : b1f;
  short*       Y    = z ? q2p : q1p;
  const int m0   = mb * 64;
  const int lane = t & 63, wave = t >> 6, quad = lane >> 4, l16 = lane & 15;

  #pragma unroll
  for (int j = 0; j < 64; j++) {
    int idx = j * 256 + t;
    int n = idx & 127, kh = idx >> 7;
    h2 p = __builtin_amdgcn_cvt_pkrtz(W[(size_t)(2 * kh) * AD_ + n] * SQL2E,
                                      W[(size_t)(2 * kh + 1) * AD_ + n] * SQL2E);
    *(h2*)&sWT[n * 264 + kh * 2] = p;
  }
  const float* xrow = &X[(size_t)(m0 + wave * 16 + l16) * KD_];
  s16x8 a[8];
  #pragma unroll
  for (int ks = 0; ks < 8; ks++) a[ks] = cvt8(xrow + ks * 32 + quad * 8);
  __syncthreads();

  f32x4 acc[8];
  #pragma unroll
  for (int nt = 0; nt < 8; nt++) acc[nt] = (f32x4){0.f, 0.f, 0.f, 0.f};
  #pragma unroll
  for (int ks = 0; ks < 8; ks++) {
    #pragma unroll
    for (int nt = 0; nt < 8; nt++) {
      s16x8 bf = *(const s16x8*)&sWT[(nt * 16 + l16) * 264 + ks * 32 + quad * 8];
      acc[nt] = mfma16(a[ks], bf, acc[nt]);
    }
  }
  #pragma unroll
  for (int nt = 0; nt < 8; nt++) {
    float bv = bias[nt * 16 + l16] * SQL2E;
    #pragma unroll
    for (int r = 0; r < 4; r++) {
      int row = m0 + wave * 16 + quad * 4 + r;
      Y[(size_t)row * AD_ + nt * 16 + l16] = f2h(acc[nt][r] + bv);
    }
  }
}

// ---------------- flash attention: R4 schedule + fixed micro ----------------
// Window: QK(i) -> softmax(i) -> storeK -> [barrier] -> loadK(i+2) ->
//         rescale -> PV(i) -> loadV(i+1).  (best-measured schedule, R4)
// Micro: hw exp2 (scale folded in proj), flat fmax tree, deferred l-sum.
__global__ __launch_bounds__(256, 2) void attn_k(
    const short* __restrict__ q1p, const short* __restrict__ q2p,
    const short* __restrict__ vt1, const short* __restrict__ vt2,
    float* __restrict__ out) {
  __shared__ __align__(16) short sK[2][64 * 136];    // 34816 B
  __shared__ __align__(16) short sP[2][4][16 * 64];  // 16384 B, XOR-swizzled
  __shared__ __align__(16) float sAl[2][68];         // alpha[64] + flags[4]

  const int t    = threadIdx.x;
  const int lane = t & 63, wave = t >> 6, quad = lane >> 4, l16 = lane & 15;
  const int id   = blockIdx.x;
  const int xcd  = id & 7, seq = id >> 3;
  const int bp   = xcd * 2 + (seq >> 5);
  const int qb   = seq & 31;
  const int b    = bp & 7, pass = bp >> 3;
  const int q0   = qb * 64;
  const short* Q  = pass ? q2p : q1p;
  const short* K  = pass ? q1p : q2p;
  const short* Vt = pass ? vt1 : vt2;
  float* O = out + (size_t)pass * ((size_t)B_ * N_ * VD_);

  const short* kp = K + (size_t)(b * N_) * AD_ + (size_t)(t >> 4) * AD_ + (t & 15) * 8;
  const short* vp = Vt + (size_t)b * 32 * (256 * 64) + wave * 4096 + lane * 8;

  s16x8 qf[4];
  #pragma unroll
  for (int ks = 0; ks < 4; ks++)
    qf[ks] = *(const s16x8*)&Q[((size_t)(b * N_ + q0 + wave * 16 + l16)) * AD_ +
                               ks * 32 + quad * 8];

  float m_i = -1e30f, l_i = 0.f;   // log2 domain; l_i quad-partial till epilogue
  f32x4 acc[16];
  #pragma unroll
  for (int c0 = 0; c0 < 16; c0++) acc[c0] = (f32x4){0.f, 0.f, 0.f, 0.f};

  s16x8 pk[4], pv[8];
  auto loadK = [&]() {
    #pragma unroll
    for (int i = 0; i < 4; i++) pk[i] = *(const s16x8*)(kp + i * 16 * AD_);
    kp += 64 * AD_;
  };
  auto loadV = [&]() {
    #pragma unroll
    for (int f = 0; f < 8; f++) pv[f] = *(const s16x8*)(vp + f * 512);
    vp += 256 * 64;
  };
  auto storeK = [&](int cb) {
    #pragma unroll
    for (int i = 0; i < 4; i++) {
      int chunk = i * 256 + t, row = chunk >> 4, c8 = chunk & 15;
      *(s16x8*)&sK[cb][row * 136 + c8 * 8] = pk[i];
    }
  };

  // prologue: sK[0] <- K(0); pk <- K(1); pv <- V(0)
  loadK(); storeK(0); loadK(); loadV();
  __syncthreads();

  int c = 0;
  for (int kt = 0; kt < 32; kt++) {
    // S^T = K Q^T : st[nt] = S[key = nt*16+quad*4+r][q = wave*16 + l16]
    f32x4 st[4];
    #pragma unroll
    for (int nt = 0; nt < 4; nt++) st[nt] = (f32x4){0.f, 0.f, 0.f, 0.f};
    __builtin_amdgcn_s_setprio(1);
    #pragma unroll
    for (int ks = 0; ks < 4; ks++) {
      #pragma unroll
      for (int nt = 0; nt < 4; nt++) {
        s16x8 kf = *(const s16x8*)&sK[c][(nt * 16 + l16) * 136 + ks * 32 + quad * 8];
        st[nt] = mfma16(kf, qf[ks], st[nt]);
      }
    }
    __builtin_amdgcn_s_setprio(0);

    // flat depth-4 max tree over 16 in-lane scores + quad combine
    float c0 = fmaxf(fmaxf(st[0][0], st[1][0]), fmaxf(st[2][0], st[3][0]));
    float c1 = fmaxf(fmaxf(st[0][1], st[1][1]), fmaxf(st[2][1], st[3][1]));
    float c2 = fmaxf(fmaxf(st[0][2], st[1][2]), fmaxf(st[2][2], st[3][2]));
    float c3 = fmaxf(fmaxf(st[0][3], st[1][3]), fmaxf(st[2][3], st[3][3]));
    float mt = fmaxf(fmaxf(c0, c1), fmaxf(c2, c3));
    mt = fmaxf(mt, __shfl_xor(mt, 16));
    mt = fmaxf(mt, __shfl_xor(mt, 32));

    // defer-max (log2 units): P <= 2^8 before refresh, f16-safe
    float alpha = 1.f;
    bool  resc  = !__all(mt - m_i <= 8.f);
    if (resc) {
      float mn = fmaxf(m_i, mt);
      alpha = exp2_hw(m_i - mn);
      l_i *= alpha;
      m_i  = mn;
    }

    // p = exp2(s - m_i); quad-partial row sums deferred to epilogue
    f32x4 psv = (f32x4){0.f, 0.f, 0.f, 0.f};
    #pragma unroll
    for (int nt = 0; nt < 4; nt++) {
      #pragma unroll
      for (int r = 0; r < 4; r++) {
        float p = exp2_hw(st[nt][r] - m_i);
        st[nt][r] = p;
        psv[r] += p;
      }
    }
    l_i += (psv[0] + psv[1]) + (psv[2] + psv[3]);

    // pack P pairs -> 8B swizzled writes into shared sP[c][wave]
    #pragma unroll
    for (int nt = 0; nt < 4; nt++) {
      union { h2 h[2]; uint2 u; } wu;
      wu.h[0] = __builtin_amdgcn_cvt_pkrtz(st[nt][0], st[nt][1]);
      wu.h[1] = __builtin_amdgcn_cvt_pkrtz(st[nt][2], st[nt][3]);
      int cp = (nt * 4 + quad) ^ ((l16 & 7) << 1);
      *(uint2*)&sP[c][wave][l16 * 64 + cp * 4] = wu.u;
    }
    if (quad == 0) sAl[c][wave * 16 + l16] = alpha;
    if (lane == 0) sAl[c][64 + wave] = resc ? 1.f : 0.f;

    // commit next K tile into the other buffer (pk already in regs)
    if (kt + 1 < 32) storeK(1 - c);

    __syncthreads();

    // prefetch K(kt+2) AFTER the barrier so the drain never waits on it
    if (kt + 2 < 32) loadK();

    // cross-wave acc rescale (rare: flag word is a broadcast read)
    f32x4 fl = *(const f32x4*)&sAl[c][64];
    if (fl[0] + fl[1] + fl[2] + fl[3] != 0.f) {
      #pragma unroll
      for (int m = 0; m < 4; m++) {
        f32x4 aR = *(const f32x4*)&sAl[c][m * 16 + quad * 4];
        #pragma unroll
        for (int v = 0; v < 4; v++) {
          #pragma unroll
          for (int r = 0; r < 4; r++) acc[m * 4 + v][r] *= aR[r];
        }
      }
    }

    // O[q][v-slice of this wave] += P @ V   (af: LDS broadcast; bf: registers)
    __builtin_amdgcn_s_setprio(1);
    #pragma unroll
    for (int m = 0; m < 4; m++) {
      #pragma unroll
      for (int ks2 = 0; ks2 < 2; ks2++) {
        int cp = (ks2 * 8 + quad * 2) ^ ((l16 & 7) << 1);
        s16x8 af = *(const s16x8*)&sP[c][m][l16 * 64 + cp * 4];
        #pragma unroll
        for (int v = 0; v < 4; v++)
          acc[m * 4 + v] = mfma16(af, pv[v * 2 + ks2], acc[m * 4 + v]);
      }
    }
    __builtin_amdgcn_s_setprio(0);

    // stream next V tile into registers (consumed after next barrier)
    if (kt + 1 < 32) loadV();
    c ^= 1;
  }

  // epilogue: combine quad-partial l across quads, share per q-row
  float lf = l_i + __shfl_xor(l_i, 16);
  lf += __shfl_xor(lf, 32);
  if (quad == 0) sAl[0][wave * 16 + l16] = lf;
  __syncthreads();
  #pragma unroll
  for (int m = 0; m < 4; m++) {
    f32x4 lv = *(const f32x4*)&sAl[0][m * 16 + quad * 4];
    #pragma unroll
    for (int r = 0; r < 4; r++) {
      float inv = 1.f / lv[r];
      int row = q0 + m * 16 + quad * 4 + r;
      #pragma unroll
      for (int v = 0; v < 4; v++)
        O[((size_t)(b * N_ + row)) * VD_ + wave * 64 + v * 16 + l16] =
            acc[m * 4 + v][r] * inv;
    }
  }
}

extern "C" void kernel_launch(void* const* d_in, const int* in_sizes, int n_in,
                              void* d_out, int out_size, void* d_ws, size_t ws_size,
                              hipStream_t stream) {
  const float* k1 = (const float*)d_in[0];
  const float* k2 = (const float*)d_in[1];
  const float* v1 = (const float*)d_in[2];
  const float* v2 = (const float*)d_in[3];
  const float* W1 = (const float*)d_in[4];
  const float* b1 = (const float*)d_in[5];
  const float* W2 = (const float*)d_in[6];
  const float* b2 = (const float*)d_in[7];

  short* ws  = (short*)d_ws;
  short* q1p = ws;                                   // 16384*128 f16 (4 MB)
  short* q2p = q1p + (size_t)16384 * 128;
  short* vt1 = q2p + (size_t)16384 * 128;            // 8*32*256*64 f16 (8.4 MB)
  short* vt2 = vt1 + (size_t)B_ * 32 * 256 * 64;
  float* out = (float*)d_out;

  prep_k<<<dim3(1024), dim3(256), 0, stream>>>(k1, k2, v1, v2, W1, b1, W2, b2,
                                               q1p, q2p, vt1, vt2);
  attn_k<<<dim3(512), dim3(256), 0, stream>>>(q1p, q2p, vt1, vt2, out);
}